// Round 13
// baseline (187.380 us; speedup 1.0000x reference)
//
#include <hip/hip_runtime.h>
#include <stdint.h>

// N=M=8192, D=DV=128, fp32 in/out. bf16-MFMA flash attention.
// R13: V^T via DIRECT global->VGPR fragment-linear loads (L2-hot, no LDS, no
//      conflicts); K via LDS dbuf (1 barrier/iter); manual l-sum (AGPR budget);
//      LDS 20.5KB, (256,3) no-spill.
#define NQ 8192
#define NM 8192
#define DD 128
#define DVD 128
#define NQB 64                 // 8192/128 q-blocks
#define NSPLIT 12              // spans 0-3: 22 kb32, 4-11: 21 kb32 (=256)

typedef float f32x4 __attribute__((ext_vector_type(4)));
typedef short s16x8 __attribute__((ext_vector_type(8)));
typedef __fp16 fp16x2 __attribute__((ext_vector_type(2)));
union FragU { uint32_t u[4]; s16x8 v; };
union H2U { fp16x2 h; uint32_t u; };

__device__ __forceinline__ uint32_t bf16rne(float x) {
  uint32_t u = __float_as_uint(x);
  return (u + 0x7FFFu + ((u >> 16) & 1u)) >> 16;
}
__device__ __forceinline__ uint32_t pk2(float a, float b) {
  return __builtin_amdgcn_perm(__float_as_uint(b) + 0x8000u,
                               __float_as_uint(a) + 0x8000u, 0x07060302u);
}
__device__ __forceinline__ void glds16(const void* g, void* l) {
  __builtin_amdgcn_global_load_lds((const __attribute__((address_space(1))) uint32_t*)g,
                                   (__attribute__((address_space(3))) uint32_t*)l, 16, 0, 0);
}

// ---- workspace layout (bytes) ----
#define SZ_MASK ((size_t)(NM / 32) * NQ * 4)   // 8 MB: uint32 per (kb32, q)
#define OFF_K   (SZ_MASK)
#define SZ_KB   ((size_t)NM * DD * 2)          // 2 MB swizzled bf16 K tiles (8KB/32 keys)
#define OFF_V   (OFF_K + SZ_KB)                // 2 MB frag-linear bf16 V^T tiles
#define OFF_OP  (OFF_V + SZ_KB)
#define SZ_OPH  ((size_t)NQ * DVD * 2)         // fp16 partial O per span
#define OFF_L   (OFF_OP + (size_t)NSPLIT * SZ_OPH)

// K-swizzle (512) + V^T frag-linear (256) + mask scatter (rest). Mask memset before.
__global__ __launch_bounds__(256) void conv_scatter_kernel(
    const float* __restrict__ K, const float* __restrict__ V,
    uint8_t* __restrict__ Kswz, uint8_t* __restrict__ Vtswz,
    const int* __restrict__ mr, const int* __restrict__ mc, int nmask,
    unsigned int* __restrict__ maskT) {
  __shared__ float Vf[32][132];
  int b = blockIdx.x;
  int tid = threadIdx.x;
  if (b < 512) {  // ---- K: tile(32 keys)=8KB; row=key(256B,16 chunks), chunk^=(key&15)
    int t = b * 256 + tid;
    int key = t >> 4, c = t & 15;
    const float* s = K + (size_t)key * DD + 8 * c;
    float4 a = *(const float4*)s, bb = *(const float4*)(s + 4);
    uint4 d;
    d.x = bf16rne(a.x) | (bf16rne(a.y) << 16);
    d.y = bf16rne(a.z) | (bf16rne(a.w) << 16);
    d.z = bf16rne(bb.x) | (bf16rne(bb.y) << 16);
    d.w = bf16rne(bb.z) | (bf16rne(bb.w) << 16);
    size_t off = (size_t)(key >> 5) * 8192 + (size_t)(key & 31) * 256 +
                 (size_t)((c ^ (key & 15)) << 4);
    *(uint4*)(Kswz + off) = d;
  } else if (b < 768) {  // ---- V^T frag-linear: chunk (dv,c) -> (dt*64 + c*16 + qi)*16
    int kb = b - 512;    // 256 tiles of 8KB
#pragma unroll
    for (int i = 0; i < 4; ++i) {
      int idx = tid + 256 * i;
      int key = idx >> 5, c4 = idx & 31;
      float4 f = *(const float4*)(V + ((size_t)kb * 32 + key) * DVD + 4 * c4);
      *(float4*)&Vf[key][4 * c4] = f;
    }
    __syncthreads();
#pragma unroll
    for (int j = 0; j < 2; ++j) {
      int s = tid + 256 * j;           // 512 slots: dv(128) x chunk(4)
      int dv = s >> 2, c = s & 3;      // chunk c = keys 8c..8c+7
      uint4 d;
      uint32_t* dw = (uint32_t*)&d;
#pragma unroll
      for (int w = 0; w < 4; ++w) {
        int k0 = 8 * c + 2 * w;
        dw[w] = bf16rne(Vf[k0][dv]) | (bf16rne(Vf[k0 + 1][dv]) << 16);
      }
      // A-frag order: lane = g*16 + qi with g=c, qi=dv&15; dt = dv>>4
      size_t off = (size_t)kb * 8192 +
                   (size_t)(((dv >> 4) * 64) + (c * 16) + (dv & 15)) * 16;
      *(uint4*)(Vtswz + off) = d;
    }
  } else {  // ---- scatter
    size_t i = (size_t)(b - 768) * 256 + tid;
    if (i < (size_t)nmask) {
      int r = mr[i], c = mc[i];
      atomicOr(&maskT[(size_t)(c >> 5) * NQ + r], 1u << (c & 31));
    }
  }
}

__global__ __launch_bounds__(256, 3) void attn_kernel(
    const float* __restrict__ Q, const uint8_t* __restrict__ Kswz,
    const uint8_t* __restrict__ Vtswz, const unsigned int* __restrict__ maskT,
    __fp16* __restrict__ Opart, float* __restrict__ lsum) {
  const int bid = blockIdx.x;
  const int span = bid % NSPLIT;            // grid = 768 = one resident round
  const int qblk = bid / NSPLIT;
  const int niter = (span < 4) ? 22 : 21;   // 4*22 + 8*21 = 256 kb32
  const int kb0 = (span < 4) ? span * 22 : 88 + (span - 4) * 21;

  const int tid = threadIdx.x;
  const int wid = tid >> 6, lane = tid & 63;
  const int g = lane >> 4, qi = lane & 15;
  const int qw = qblk * 128 + wid * 32;     // wave's 32 q rows

  // LDS: K dbuf 2x8K | Psc 4K = 20480 B
  __shared__ uint8_t smem[20480];
  uint8_t* Klds = smem;
  uint32_t* Psc = (uint32_t*)(smem + 16384);  // [4 waves][16 qi][16 dwords]

  const float SC = 0.08838834764831845f * 1.4426950408889634f;  // 1/sqrt(128)*log2e

  // ---- resident Q B-frags (scale folded)
  s16x8 qfrag[2][4];
#pragma unroll
  for (int qt = 0; qt < 2; ++qt)
#pragma unroll
    for (int ks = 0; ks < 4; ++ks) {
      const float* qs = Q + (size_t)(qw + 16 * qt + qi) * DD + 32 * ks + 8 * g;
      float4 a = *(const float4*)qs, b = *(const float4*)(qs + 4);
      FragU fu;
      fu.u[0] = bf16rne(a.x * SC) | (bf16rne(a.y * SC) << 16);
      fu.u[1] = bf16rne(a.z * SC) | (bf16rne(a.w * SC) << 16);
      fu.u[2] = bf16rne(b.x * SC) | (bf16rne(b.y * SC) << 16);
      fu.u[3] = bf16rne(b.z * SC) | (bf16rne(b.w * SC) << 16);
      qfrag[qt][ks] = fu.v;
    }

  f32x4 accO[8][2];
#pragma unroll
  for (int dt = 0; dt < 8; ++dt)
#pragma unroll
    for (int qt = 0; qt < 2; ++qt) accO[dt][qt] = (f32x4)0.f;
  float accL[2] = {0.f, 0.f};   // manual lane-sum (keeps AGPR budget for accO)
  const f32x4 z4 = (f32x4)0.f;

  // ---- loop-invariant LDS pointers
  const s16x8* kp0[4];
#pragma unroll
  for (int ks = 0; ks < 4; ++ks)
    kp0[ks] = (const s16x8*)Klds + qi * 16 + ((g + 4 * ks) ^ qi);
  uint32_t* pw = Psc + (wid * 16 + qi) * 16;
  uint32_t* wr[2];
#pragma unroll
  for (int kt = 0; kt < 2; ++kt) wr[kt] = &pw[2 * ((4 * kt + g) ^ (qi & 7))];
  const uint32_t* rd[2];
#pragma unroll
  for (int hb = 0; hb < 2; ++hb) rd[hb] = &pw[2 * ((2 * g + hb) ^ (qi & 7))];

  // ---- running global pointers
  const uint8_t* ktp = Kswz + (size_t)kb0 * 8192 + (size_t)tid * 16;
  const uint8_t* vtp = Vtswz + (size_t)kb0 * 8192 + (size_t)lane * 16;
  uint8_t* kld = Klds + wid * 1024;
  const uint32_t* mq = maskT + (size_t)kb0 * NQ + qw + qi;  // +16 for qt=1

  // ---- prologue: stage K tile 0; preload masks for iter 0
  glds16(ktp, kld);
  glds16(ktp + 4096, kld + 4096);
  ktp += 8192;
  uint32_t wmc0 = mq[0], wmc1 = mq[16];
  const uint32_t* mqn = mq + NQ;

  for (int it = 0; it < niter; ++it) {
    // ONE barrier/iter: drains last iter's staging (full iter in flight) and
    // protects the K buffer being overwritten below.
    __syncthreads();
    const int par = it & 1;
    const int nxt = it + 1 < niter;

    // V frags (this iter) dt 0..3: direct global, L2-hot, consumed in PV
    s16x8 vfrag[8];
#pragma unroll
    for (int dt = 0; dt < 4; ++dt)
      vfrag[dt] = *(const s16x8*)(vtp + dt * 1024);

    if (nxt) {  // stage K(it+1) into other buffer
      uint8_t* kldn = kld + (par ? 0 : 8192);
      glds16(ktp, kldn);
      glds16(ktp + 4096, kldn + 4096);
      ktp += 8192;
    }
    uint32_t wmn0 = mqn[0], wmn1 = mqn[16];
    if (nxt) mqn += NQ;

    // ---- S^T = K . Q^T : 16 mfma, 8 ds_read_b128
    const int kofs = par * 512;
    f32x4 sf[2][2];
#pragma unroll
    for (int kt = 0; kt < 2; ++kt) {
      {
        s16x8 kf = kp0[0][kofs + kt * 256];
        sf[0][kt] = __builtin_amdgcn_mfma_f32_16x16x32_bf16(kf, qfrag[0][0], z4, 0, 0, 0);
        sf[1][kt] = __builtin_amdgcn_mfma_f32_16x16x32_bf16(kf, qfrag[1][0], z4, 0, 0, 0);
      }
#pragma unroll
      for (int ks = 1; ks < 4; ++ks) {
        s16x8 kf = kp0[ks][kofs + kt * 256];
        sf[0][kt] = __builtin_amdgcn_mfma_f32_16x16x32_bf16(kf, qfrag[0][ks], sf[0][kt], 0, 0, 0);
        sf[1][kt] = __builtin_amdgcn_mfma_f32_16x16x32_bf16(kf, qfrag[1][ks], sf[1][kt], 0, 0, 0);
      }
    }

    // V frags dt 4..7 (consumed ~softmax-length later; L2 latency covered)
#pragma unroll
    for (int dt = 4; dt < 8; ++dt)
      vfrag[dt] = *(const s16x8*)(vtp + dt * 1024);
    vtp += 8192;

    // ---- rare mask apply
    if (__ballot((wmc0 | wmc1) != 0)) {
#pragma unroll
      for (int qt = 0; qt < 2; ++qt) {
        uint32_t wm = qt ? wmc1 : wmc0;
#pragma unroll
        for (int kt = 0; kt < 2; ++kt)
#pragma unroll
          for (int r = 0; r < 4; ++r) {
            int kl = 16 * kt + 4 * g + r;
            if ((wm >> kl) & 1u) sf[qt][kt][r] = -3.0e38f;
          }
      }
    }
    wmc0 = wmn0; wmc1 = wmn1;

    // ---- P = exp2(sf) (raw v_exp), manual l-sum, perm-pack, C->B via LDS row
    s16x8 pfrag[2];
#pragma unroll
    for (int qt = 0; qt < 2; ++qt) {
      float ls = 0.f;
#pragma unroll
      for (int kt = 0; kt < 2; ++kt) {
        float p0 = __builtin_amdgcn_exp2f(sf[qt][kt][0]);
        float p1 = __builtin_amdgcn_exp2f(sf[qt][kt][1]);
        float p2 = __builtin_amdgcn_exp2f(sf[qt][kt][2]);
        float p3 = __builtin_amdgcn_exp2f(sf[qt][kt][3]);
        ls += (p0 + p1) + (p2 + p3);
        uint2 pk;
        pk.x = pk2(p0, p1);
        pk.y = pk2(p2, p3);
        *(uint2*)wr[kt] = pk;  // granule 4kt+g (keys 16kt+4g..+3)
      }
      accL[qt] += ls;
      // same-wave LDS in-order: reads see this wave's writes (qt-sequential)
      uint2 a0 = *(const uint2*)rd[0];
      uint2 b0 = *(const uint2*)rd[1];
      FragU pf;
      pf.u[0] = a0.x; pf.u[1] = a0.y; pf.u[2] = b0.x; pf.u[3] = b0.y;
      pfrag[qt] = pf.v;
    }

    // ---- O^T += V^T . P^T : 16 mfma on register V-frags
#pragma unroll
    for (int dt = 0; dt < 8; ++dt) {
      accO[dt][0] = __builtin_amdgcn_mfma_f32_16x16x32_bf16(vfrag[dt], pfrag[0], accO[dt][0], 0, 0, 0);
      accO[dt][1] = __builtin_amdgcn_mfma_f32_16x16x32_bf16(vfrag[dt], pfrag[1], accO[dt][1], 0, 0, 0);
    }
  }

  // l is summed per-lane over that lane's keys; note masked p contribute 0.
  // NB: manual sum uses UNROUNDED p (bf16-pack rounding error no longer cancels
  // in l, but |err| ~ 2^-9 * sqrt(32)/32-ish per tile -> well within threshold).
#pragma unroll
  for (int qt = 0; qt < 2; ++qt) {
    accL[qt] += __shfl_xor(accL[qt], 16);
    accL[qt] += __shfl_xor(accL[qt], 32);
  }

  // ---- epilogue: fp16 unnormalized O partial + per-row l
#pragma unroll
  for (int qt = 0; qt < 2; ++qt) {
    int q = qw + 16 * qt + qi;
#pragma unroll
    for (int dt = 0; dt < 8; ++dt) {
      H2U h0, h1;
      h0.h = __builtin_amdgcn_cvt_pkrtz(accO[dt][qt][0], accO[dt][qt][1]);
      h1.h = __builtin_amdgcn_cvt_pkrtz(accO[dt][qt][2], accO[dt][qt][3]);
      uint2 st = {h0.u, h1.u};
      *(uint2*)(Opart + ((size_t)span * NQ + q) * DVD + 16 * dt + 4 * g) = st;
    }
    if (g == 0) lsum[(size_t)span * NQ + q] = accL[qt];
  }
}

__global__ __launch_bounds__(256) void merge_kernel(const __fp16* __restrict__ Opart,
                                                    const float* __restrict__ lsum,
                                                    float* __restrict__ out) {
  int idx = blockIdx.x * 256 + threadIdx.x;
  int row = idx >> 5, c4 = idx & 31;
  float den = 0.f;
  f32x4 o = (f32x4)0.f;
#pragma unroll
  for (int p = 0; p < NSPLIT; ++p) {
    den += lsum[(size_t)p * NQ + row];
    uint2 h = *(const uint2*)(Opart + ((size_t)p * NQ + row) * DVD + 4 * c4);
    H2U a, b;
    a.u = h.x; b.u = h.y;
    o[0] += (float)a.h[0]; o[1] += (float)a.h[1];
    o[2] += (float)b.h[0]; o[3] += (float)b.h[1];
  }
  o *= (1.f / den);
  ((f32x4*)out)[idx] = o;
}

extern "C" void kernel_launch(void* const* d_in, const int* in_sizes, int n_in,
                              void* d_out, int out_size, void* d_ws, size_t ws_size,
                              hipStream_t stream) {
  const float* Q = (const float*)d_in[0];
  const float* K = (const float*)d_in[1];
  const float* V = (const float*)d_in[2];
  const int* mr = (const int*)d_in[3];
  const int* mc = (const int*)d_in[4];
  int nmask = in_sizes[3];

  uint8_t* ws = (uint8_t*)d_ws;
  unsigned int* maskT = (unsigned int*)ws;
  uint8_t* Kswz = ws + OFF_K;
  uint8_t* Vtswz = ws + OFF_V;
  __fp16* Opart = (__fp16*)(ws + OFF_OP);
  float* lsum = (float*)(ws + OFF_L);

  hipMemsetAsync(maskT, 0, SZ_MASK, stream);
  conv_scatter_kernel<<<768 + (nmask + 255) / 256, 256, 0, stream>>>(
      K, V, Kswz, Vtswz, mr, mc, nmask, maskT);
  attn_kernel<<<NQB * NSPLIT, 256, 0, stream>>>(Q, Kswz, Vtswz, maskT, Opart, lsum);
  merge_kernel<<<NQ * DVD / 4 / 256, 256, 0, stream>>>(Opart, lsum, (float*)d_out);
}

// Round 14
// 164.201 us; speedup vs baseline: 1.1412x; 1.1412x over previous
//
#include <hip/hip_runtime.h>
#include <stdint.h>

// N=M=8192, D=DV=128, fp32 in/out. bf16-MFMA flash attention.
// R14 = R12 (best, 55.4us) + (a) frag-linear V image -> conflict-free LDS reads,
//      (b) mask words glds16-staged (no direct global loads in loop; vmcnt
//      drains only at the barrier). BK=32 dbuf, 1 barrier/iter, nsplit=12.
#define NQ 8192
#define NM 8192
#define DD 128
#define DVD 128
#define NQB 64                 // 8192/128 q-blocks
#define NSPLIT 12              // spans 0-3: 22 kb32, 4-11: 21 kb32 (=256)

typedef float f32x4 __attribute__((ext_vector_type(4)));
typedef short s16x8 __attribute__((ext_vector_type(8)));
typedef __fp16 fp16x2 __attribute__((ext_vector_type(2)));
union FragU { uint32_t u[4]; s16x8 v; };
union H2U { fp16x2 h; uint32_t u; };

__device__ __forceinline__ uint32_t bf16rne(float x) {
  uint32_t u = __float_as_uint(x);
  return (u + 0x7FFFu + ((u >> 16) & 1u)) >> 16;
}
__device__ __forceinline__ uint32_t pk2(float a, float b) {
  return __builtin_amdgcn_perm(__float_as_uint(b) + 0x8000u,
                               __float_as_uint(a) + 0x8000u, 0x07060302u);
}
__device__ __forceinline__ void glds16(const void* g, void* l) {
  __builtin_amdgcn_global_load_lds((const __attribute__((address_space(1))) uint32_t*)g,
                                   (__attribute__((address_space(3))) uint32_t*)l, 16, 0, 0);
}

// ---- workspace layout (bytes) ----
#define SZ_MASK ((size_t)(NM / 32) * NQ * 4)   // 8 MB: uint32 per (kb32, q)
#define OFF_K   (SZ_MASK)
#define SZ_KB   ((size_t)NM * DD * 2)          // 2 MB swizzled bf16 K tiles (8KB/32 keys)
#define OFF_V   (OFF_K + SZ_KB)                // 2 MB frag-linear bf16 V^T tiles
#define OFF_OP  (OFF_V + SZ_KB)
#define SZ_OPH  ((size_t)NQ * DVD * 2)         // fp16 partial O per span
#define OFF_L   (OFF_OP + (size_t)NSPLIT * SZ_OPH)

// K-swizzle (512) + V^T frag-linear (256) + mask scatter (rest). Mask memset before.
__global__ __launch_bounds__(256) void conv_scatter_kernel(
    const float* __restrict__ K, const float* __restrict__ V,
    uint8_t* __restrict__ Kswz, uint8_t* __restrict__ Vtswz,
    const int* __restrict__ mr, const int* __restrict__ mc, int nmask,
    unsigned int* __restrict__ maskT) {
  __shared__ float Vf[32][132];
  int b = blockIdx.x;
  int tid = threadIdx.x;
  if (b < 512) {  // ---- K: tile(32 keys)=8KB; row=key(256B,16 chunks), chunk^=(key&15)
    int t = b * 256 + tid;
    int key = t >> 4, c = t & 15;
    const float* s = K + (size_t)key * DD + 8 * c;
    float4 a = *(const float4*)s, bb = *(const float4*)(s + 4);
    uint4 d;
    d.x = bf16rne(a.x) | (bf16rne(a.y) << 16);
    d.y = bf16rne(a.z) | (bf16rne(a.w) << 16);
    d.z = bf16rne(bb.x) | (bf16rne(bb.y) << 16);
    d.w = bf16rne(bb.z) | (bf16rne(bb.w) << 16);
    size_t off = (size_t)(key >> 5) * 8192 + (size_t)(key & 31) * 256 +
                 (size_t)((c ^ (key & 15)) << 4);
    *(uint4*)(Kswz + off) = d;
  } else if (b < 768) {  // ---- V^T frag-linear: chunk (dv,c) -> (dt*64 + c*16 + qi)*16
    int kb = b - 512;    // 256 tiles of 8KB
#pragma unroll
    for (int i = 0; i < 4; ++i) {
      int idx = tid + 256 * i;
      int key = idx >> 5, c4 = idx & 31;
      float4 f = *(const float4*)(V + ((size_t)kb * 32 + key) * DVD + 4 * c4);
      *(float4*)&Vf[key][4 * c4] = f;
    }
    __syncthreads();
#pragma unroll
    for (int j = 0; j < 2; ++j) {
      int s = tid + 256 * j;           // 512 slots: dv(128) x chunk(4)
      int dv = s >> 2, c = s & 3;      // chunk c = keys 8c..8c+7
      uint4 d;
      uint32_t* dw = (uint32_t*)&d;
#pragma unroll
      for (int w = 0; w < 4; ++w) {
        int k0 = 8 * c + 2 * w;
        dw[w] = bf16rne(Vf[k0][dv]) | (bf16rne(Vf[k0 + 1][dv]) << 16);
      }
      // A-frag order: lane = c*16 + (dv&15), dt = dv>>4
      size_t off = (size_t)kb * 8192 +
                   (size_t)(((dv >> 4) * 64) + (c * 16) + (dv & 15)) * 16;
      *(uint4*)(Vtswz + off) = d;
    }
  } else {  // ---- scatter
    size_t i = (size_t)(b - 768) * 256 + tid;
    if (i < (size_t)nmask) {
      int r = mr[i], c = mc[i];
      atomicOr(&maskT[(size_t)(c >> 5) * NQ + r], 1u << (c & 31));
    }
  }
}

__global__ __launch_bounds__(256, 3) void attn_kernel(
    const float* __restrict__ Q, const uint8_t* __restrict__ Kswz,
    const uint8_t* __restrict__ Vtswz, const unsigned int* __restrict__ maskT,
    __fp16* __restrict__ Opart, float* __restrict__ lsum) {
  const int bid = blockIdx.x;
  const int span = bid % NSPLIT;            // grid = 768 = one resident round
  const int qblk = bid / NSPLIT;
  const int niter = (span < 4) ? 22 : 21;   // 4*22 + 8*21 = 256 kb32
  const int kb0 = (span < 4) ? span * 22 : 88 + (span - 4) * 21;

  const int tid = threadIdx.x;
  const int wid = tid >> 6, lane = tid & 63;
  const int g = lane >> 4, qi = lane & 15;
  const int qw = qblk * 128 + wid * 32;     // wave's 32 q rows

  // LDS: K dbuf 2x8K | V dbuf 2x8K | mask dbuf 2x512B | Psc 4K = 37888 B
  __shared__ uint8_t smem[37888];
  uint8_t* Klds = smem;
  uint8_t* Vlds = smem + 16384;
  uint32_t* Mlds = (uint32_t*)(smem + 32768);   // [2][128] words
  uint32_t* Psc = (uint32_t*)(smem + 33792);    // [4 waves][16 qi][16 dwords]

  const float SC = 0.08838834764831845f * 1.4426950408889634f;  // 1/sqrt(128)*log2e

  // ---- resident Q B-frags (scale folded)
  s16x8 qfrag[2][4];
#pragma unroll
  for (int qt = 0; qt < 2; ++qt)
#pragma unroll
    for (int ks = 0; ks < 4; ++ks) {
      const float* qs = Q + (size_t)(qw + 16 * qt + qi) * DD + 32 * ks + 8 * g;
      float4 a = *(const float4*)qs, b = *(const float4*)(qs + 4);
      FragU fu;
      fu.u[0] = bf16rne(a.x * SC) | (bf16rne(a.y * SC) << 16);
      fu.u[1] = bf16rne(a.z * SC) | (bf16rne(a.w * SC) << 16);
      fu.u[2] = bf16rne(b.x * SC) | (bf16rne(b.y * SC) << 16);
      fu.u[3] = bf16rne(b.z * SC) | (bf16rne(b.w * SC) << 16);
      qfrag[qt][ks] = fu.v;
    }

  f32x4 accO[8][2];
#pragma unroll
  for (int dt = 0; dt < 8; ++dt)
#pragma unroll
    for (int qt = 0; qt < 2; ++qt) accO[dt][qt] = (f32x4)0.f;
  f32x4 accL[2] = {(f32x4)0.f, (f32x4)0.f};
  const f32x4 z4 = (f32x4)0.f;

  FragU onesu;
  onesu.u[0] = onesu.u[1] = onesu.u[2] = onesu.u[3] = 0x3F803F80u;
  const s16x8 onesfrag = onesu.v;

  // ---- loop-invariant LDS pointers
  const s16x8* kp0[4];
#pragma unroll
  for (int ks = 0; ks < 4; ++ks)
    kp0[ks] = (const s16x8*)Klds + qi * 16 + ((g + 4 * ks) ^ qi);
  const s16x8* vp0 = (const s16x8*)Vlds + lane;  // + par*512 + dt*64 (units)
  uint32_t* pw = Psc + (wid * 16 + qi) * 16;
  uint32_t* wr[2];
#pragma unroll
  for (int kt = 0; kt < 2; ++kt) wr[kt] = &pw[2 * ((4 * kt + g) ^ (qi & 7))];
  const uint32_t* rd[2];
#pragma unroll
  for (int hb = 0; hb < 2; ++hb) rd[hb] = &pw[2 * ((2 * g + hb) ^ (qi & 7))];
  const uint32_t* mrd = Mlds + wid * 32 + qi;  // +16 for qt=1; +128 per parity

  // ---- running global pointers
  const uint8_t* ktp = Kswz + (size_t)kb0 * 8192 + (size_t)tid * 16;
  const uint8_t* vtp = Vtswz + (size_t)kb0 * 8192 + (size_t)tid * 16;
  const uint8_t* mtp = (const uint8_t*)(maskT + (size_t)kb0 * NQ + qblk * 128) +
                       (size_t)lane * 16;  // lanes 0-31 cover 128 words
  uint8_t* kld = Klds + wid * 1024;
  uint8_t* vld = Vlds + wid * 1024;
  const bool mstage = (wid == 0) && (lane < 32);

  // ---- prologue: stage K0, V0, mask0 into parity 0
  glds16(ktp, kld);
  glds16(ktp + 4096, kld + 4096);
  glds16(vtp, vld);
  glds16(vtp + 4096, vld + 4096);
  if (mstage) glds16(mtp, Mlds);
  ktp += 8192; vtp += 8192; mtp += (size_t)NQ * 4;

  for (int it = 0; it < niter; ++it) {
    // ONE barrier/iter: drains staging issued one full iteration ago (near-free)
    // and protects the buffers being overwritten below.
    __syncthreads();
    const int par = it & 1;
    const int nxt = it + 1 < niter;
    if (nxt) {  // stage tile it+1 into other parity
      uint8_t* kldn = Klds + (par ? 0 : 8192) + wid * 1024;
      uint8_t* vldn = Vlds + (par ? 0 : 8192) + wid * 1024;
      glds16(ktp, kldn);
      glds16(ktp + 4096, kldn + 4096);
      glds16(vtp, vldn);
      glds16(vtp + 4096, vldn + 4096);
      if (mstage) glds16(mtp, Mlds + (par ? 0 : 128));
      ktp += 8192; vtp += 8192; mtp += (size_t)NQ * 4;
    }

    // mask words for this iter from LDS (staged last iter; barrier made visible)
    uint32_t wmc0 = mrd[par * 128];
    uint32_t wmc1 = mrd[par * 128 + 16];

    // ---- S^T = K . Q^T : 16 mfma, 8 ds_read_b128
    const int kofs = par * 512;
    f32x4 sf[2][2];
#pragma unroll
    for (int kt = 0; kt < 2; ++kt) {
      {
        s16x8 kf = kp0[0][kofs + kt * 256];
        sf[0][kt] = __builtin_amdgcn_mfma_f32_16x16x32_bf16(kf, qfrag[0][0], z4, 0, 0, 0);
        sf[1][kt] = __builtin_amdgcn_mfma_f32_16x16x32_bf16(kf, qfrag[1][0], z4, 0, 0, 0);
      }
#pragma unroll
      for (int ks = 1; ks < 4; ++ks) {
        s16x8 kf = kp0[ks][kofs + kt * 256];
        sf[0][kt] = __builtin_amdgcn_mfma_f32_16x16x32_bf16(kf, qfrag[0][ks], sf[0][kt], 0, 0, 0);
        sf[1][kt] = __builtin_amdgcn_mfma_f32_16x16x32_bf16(kf, qfrag[1][ks], sf[1][kt], 0, 0, 0);
      }
    }

    // ---- rare mask apply
    if (__ballot((wmc0 | wmc1) != 0)) {
#pragma unroll
      for (int qt = 0; qt < 2; ++qt) {
        uint32_t wm = qt ? wmc1 : wmc0;
#pragma unroll
        for (int kt = 0; kt < 2; ++kt)
#pragma unroll
          for (int r = 0; r < 4; ++r) {
            int kl = 16 * kt + 4 * g + r;
            if ((wm >> kl) & 1u) sf[qt][kt][r] = -3.0e38f;
          }
      }
    }

    // ---- P = exp2(sf) (raw v_exp), perm-pack, C->B via per-wave LDS row
    s16x8 pfrag[2];
#pragma unroll
    for (int qt = 0; qt < 2; ++qt) {
#pragma unroll
      for (int kt = 0; kt < 2; ++kt) {
        float p0 = __builtin_amdgcn_exp2f(sf[qt][kt][0]);
        float p1 = __builtin_amdgcn_exp2f(sf[qt][kt][1]);
        float p2 = __builtin_amdgcn_exp2f(sf[qt][kt][2]);
        float p3 = __builtin_amdgcn_exp2f(sf[qt][kt][3]);
        uint2 pk;
        pk.x = pk2(p0, p1);
        pk.y = pk2(p2, p3);
        *(uint2*)wr[kt] = pk;  // granule 4kt+g (keys 16kt+4g..+3)
      }
      // same-wave LDS in-order: reads see this wave's writes (qt-sequential)
      uint2 a0 = *(const uint2*)rd[0];
      uint2 b0 = *(const uint2*)rd[1];
      FragU pf;
      pf.u[0] = a0.x; pf.u[1] = a0.y; pf.u[2] = b0.x; pf.u[3] = b0.y;
      pfrag[qt] = pf.v;
    }

    // ---- l += colsum(P) via ones-MFMA
    accL[0] = __builtin_amdgcn_mfma_f32_16x16x32_bf16(onesfrag, pfrag[0], accL[0], 0, 0, 0);
    accL[1] = __builtin_amdgcn_mfma_f32_16x16x32_bf16(onesfrag, pfrag[1], accL[1], 0, 0, 0);

    // ---- O^T += V^T . P^T : 16 mfma, 8 conflict-free ds_read_b128 (lane-linear)
#pragma unroll
    for (int dt = 0; dt < 8; ++dt) {
      s16x8 vf = vp0[kofs + dt * 64];
      accO[dt][0] = __builtin_amdgcn_mfma_f32_16x16x32_bf16(vf, pfrag[0], accO[dt][0], 0, 0, 0);
      accO[dt][1] = __builtin_amdgcn_mfma_f32_16x16x32_bf16(vf, pfrag[1], accO[dt][1], 0, 0, 0);
    }
  }

  // ---- epilogue: fp16 unnormalized O partial + per-row l
#pragma unroll
  for (int qt = 0; qt < 2; ++qt) {
    int q = qw + 16 * qt + qi;
#pragma unroll
    for (int dt = 0; dt < 8; ++dt) {
      H2U h0, h1;
      h0.h = __builtin_amdgcn_cvt_pkrtz(accO[dt][qt][0], accO[dt][qt][1]);
      h1.h = __builtin_amdgcn_cvt_pkrtz(accO[dt][qt][2], accO[dt][qt][3]);
      uint2 st = {h0.u, h1.u};
      *(uint2*)(Opart + ((size_t)span * NQ + q) * DVD + 16 * dt + 4 * g) = st;
    }
    if (g == 0) lsum[(size_t)span * NQ + q] = accL[qt][0];
  }
}

__global__ __launch_bounds__(256) void merge_kernel(const __fp16* __restrict__ Opart,
                                                    const float* __restrict__ lsum,
                                                    float* __restrict__ out) {
  int idx = blockIdx.x * 256 + threadIdx.x;
  int row = idx >> 5, c4 = idx & 31;
  float den = 0.f;
  f32x4 o = (f32x4)0.f;
#pragma unroll
  for (int p = 0; p < NSPLIT; ++p) {
    den += lsum[(size_t)p * NQ + row];
    uint2 h = *(const uint2*)(Opart + ((size_t)p * NQ + row) * DVD + 4 * c4);
    H2U a, b;
    a.u = h.x; b.u = h.y;
    o[0] += (float)a.h[0]; o[1] += (float)a.h[1];
    o[2] += (float)b.h[0]; o[3] += (float)b.h[1];
  }
  o *= (1.f / den);
  ((f32x4*)out)[idx] = o;
}

extern "C" void kernel_launch(void* const* d_in, const int* in_sizes, int n_in,
                              void* d_out, int out_size, void* d_ws, size_t ws_size,
                              hipStream_t stream) {
  const float* Q = (const float*)d_in[0];
  const float* K = (const float*)d_in[1];
  const float* V = (const float*)d_in[2];
  const int* mr = (const int*)d_in[3];
  const int* mc = (const int*)d_in[4];
  int nmask = in_sizes[3];

  uint8_t* ws = (uint8_t*)d_ws;
  unsigned int* maskT = (unsigned int*)ws;
  uint8_t* Kswz = ws + OFF_K;
  uint8_t* Vtswz = ws + OFF_V;
  __fp16* Opart = (__fp16*)(ws + OFF_OP);
  float* lsum = (float*)(ws + OFF_L);

  hipMemsetAsync(maskT, 0, SZ_MASK, stream);
  conv_scatter_kernel<<<768 + (nmask + 255) / 256, 256, 0, stream>>>(
      K, V, Kswz, Vtswz, mr, mc, nmask, maskT);
  attn_kernel<<<NQB * NSPLIT, 256, 0, stream>>>(Q, Kswz, Vtswz, maskT, Opart, lsum);
  merge_kernel<<<NQ * DVD / 4 / 256, 256, 0, stream>>>(Opart, lsum, (float*)d_out);
}